// Round 10
// baseline (119.137 us; speedup 1.0000x reference)
//
#include <hip/hip_runtime.h>
#include <hip/hip_bf16.h>

// Problem constants
#define BB 4
#define NN 4096
#define JSPLIT 8
#define LOG2E 1.4426950408889634f

typedef __attribute__((ext_vector_type(8))) short short8;   // 8 bf16 (4 VGPRs)
typedef __attribute__((ext_vector_type(4))) float f32x4;    // MFMA C/D
typedef __attribute__((ext_vector_type(4))) int   i32x4;

// ws layout (float units):
//  qb     bf16 [4][4096][8]                @f 0        (pre-scaled by log2e)
//  kb     bf16 [4][4096][8]                @f 65536
//  vb     bf16 [4][64][4][2][4][16][8]     @f 131072   (B-fragment order)
//  wfragg bf16 [18][64][8]                 @f 1179648  A-frags of W
//  bias   f32  [144]                       @f 1184256
//  pout   bf16 [8][4][64][4096]            @f 1184400
//  pl     f32  [8][4][4096]                @f 5378704

__device__ __forceinline__ unsigned short f2bf(float f) {        // RN
    unsigned u = __float_as_uint(f);
    return (unsigned short)((u + 0x7FFFu + ((u >> 16) & 1u)) >> 16);
}
__device__ __forceinline__ unsigned short f2bfz(float f) {       // RTZ (cheap)
    return (unsigned short)(__float_as_uint(f) >> 16);
}
__device__ __forceinline__ int packbf(float lo, float hi) {      // RTZ pair pack
    return (int)((__float_as_uint(lo) >> 16) | (__float_as_uint(hi) & 0xFFFF0000u));
}

// ---------------------------------------------------------------------------
// Kernel 0: bake W (144x64) into bf16 MFMA A-fragments + bias, once.
// Wq/bq pre-scaled by log2e so attn uses native v_exp_f32 (2^x).
// ---------------------------------------------------------------------------
__global__ __launch_bounds__(256) void wsetup_kernel(
    const float* __restrict__ Wq, const float* __restrict__ bq,
    const float* __restrict__ Wk, const float* __restrict__ bk,
    const float* __restrict__ Wv, const float* __restrict__ bv,
    const float* __restrict__ W1, const float* __restrict__ b1,
    unsigned short* __restrict__ wfragg, float* __restrict__ bias)
{
    const int f = blockIdx.x * 256 + threadIdx.x;   // 0..9215
    const int o = f >> 6, c = f & 63;
    float wv;
    if (f < 512)        wv = Wq[f] * LOG2E;
    else if (f < 1024)  wv = Wk[f - 512];
    else if (f < 5120)  wv = Wv[f - 1024];
    else                wv = W1[f - 5120];
    const int chunk = o >> 4, ks = c >> 5, quad = (c >> 3) & 3, jj = c & 7;
    wfragg[(((chunk * 2 + ks) * 64) + quad * 16 + (o & 15)) * 8 + jj] = f2bf(wv);
    if (blockIdx.x == 0 && threadIdx.x < 144) {
        const int t = threadIdx.x;
        bias[t] = (t < 8) ? bq[t] * LOG2E : (t < 16) ? bk[t - 8]
                : (t < 80) ? bv[t - 16] : b1[t - 80];
    }
}

// ---------------------------------------------------------------------------
// Kernel 1: fused 1x1 convs via MFMA, W-fragments per-lane from ws.
// grid 1024 = 4 b x 256 n-tiles of 16; block 256.
// ---------------------------------------------------------------------------
__global__ __launch_bounds__(256) void proj_kernel(
    const float* __restrict__ x,
    const unsigned short* __restrict__ wfragg, const float* __restrict__ bias,
    unsigned short* __restrict__ qb, unsigned short* __restrict__ kb,
    unsigned short* __restrict__ vb, float* __restrict__ out)
{
    __shared__ __align__(16) unsigned short xh[16 * 80];  // [n][c] bf16
    __shared__ float bl[144];

    const int tid = threadIdx.x;
    const int blk = blockIdx.x;
    const int b  = blk >> 8;
    const int n0 = (blk & 255) * 16;

    if (tid < 144) bl[tid] = bias[tid];
    #pragma unroll
    for (int e = tid; e < 1024; e += 256) {
        const int c = e >> 4, nl = e & 15;
        xh[nl * 80 + c] = f2bf(x[(b * 64 + c) * NN + n0 + nl]);
    }
    __syncthreads();

    const int w = tid >> 6, lane = tid & 63;
    const int q = lane >> 4, l15 = lane & 15;
    const int n = n0 + l15;

    const short8 xf0 = *(const short8*)&xh[l15 * 80 + q * 8];
    const short8 xf1 = *(const short8*)&xh[l15 * 80 + 32 + q * 8];
    const f32x4 zf = {0.f, 0.f, 0.f, 0.f};

    const int vt = n >> 6, vs = (n >> 5) & 1, vq = (n >> 3) & 3, vjj = n & 7;

    // wave w handles chunks {w, w+4}; wave 0 also chunk 8
    #pragma unroll
    for (int ci = 0; ci < 3; ++ci) {
        if (ci == 2 && w != 0) break;
        const int chunk = (ci == 2) ? 8 : (w + ci * 4);
        const short8 a0 = *(const short8*)&wfragg[((chunk * 2 + 0) * 64 + lane) * 8];
        const short8 a1 = *(const short8*)&wfragg[((chunk * 2 + 1) * 64 + lane) * 8];
        f32x4 d = __builtin_amdgcn_mfma_f32_16x16x32_bf16(a0, xf0, zf, 0, 0, 0);
        d = __builtin_amdgcn_mfma_f32_16x16x32_bf16(a1, xf1, d, 0, 0, 0);
        #pragma unroll
        for (int r = 0; r < 4; ++r) {
            const int o = chunk * 16 + q * 4 + r;
            const float val = d[r] + bl[o];
            if (o < 8) {
                qb[(size_t)(b * NN + n) * 8 + o] = f2bfz(val);
            } else if (o < 16) {
                kb[(size_t)(b * NN + n) * 8 + (o - 8)] = f2bfz(val);
            } else if (o < 80) {
                const int c = o - 16;
                size_t idx = ((((size_t)((b * 64 + vt) * 4 + (c >> 4)) * 2 + vs) * 4 + vq) * 16
                              + (c & 15)) * 8 + vjj;
                vb[idx] = f2bfz(val);
            } else {
                out[(size_t)(b * 64 + (o - 80)) * NN + n] = val;   // x1 fp32 exact
            }
        }
    }
}

// ---------------------------------------------------------------------------
// Kernel 2: MFMA flash attention, bpermute P-transform (no pw LDS, no DS
// ordering hazard, tiles independent). grid 2048 encoded it*32+js*4+b so
// each XCD (blk&7 round-robin) sees a single (b, js-parity) K/V slice.
// block 256 = 4 independent waves, no barriers.
// ---------------------------------------------------------------------------
__global__ void attn_kernel(
    const unsigned short* __restrict__ qws,
    const unsigned short* __restrict__ kws,
    const unsigned short* __restrict__ vfrag,
    unsigned short* __restrict__ pout, float* __restrict__ pl)
{
    __shared__ __align__(16) float olds[4][64][17];   // epilogue transpose only

    const int tid  = threadIdx.x;
    const int w    = tid >> 6;
    const int lane = tid & 63;
    const int q    = lane >> 4;
    const int l15  = lane & 15;

    const int blk = blockIdx.x;       // = it*32 + js*4 + b
    const int b   = blk & 3;
    const int js  = (blk >> 2) & 7;
    const int it  = blk >> 5;
    const int i0  = it * 64;

    const short8 z8 = {0, 0, 0, 0, 0, 0, 0, 0};
    const f32x4 zf = {0.f, 0.f, 0.f, 0.f};

    // Q as B-operand (pre-scaled by log2e): quads 1..3 zeroed (dk padded 8->32)
    short8 qf = *(const short8*)&qws[(size_t)(b * NN + i0 + w * 16 + l15) * 8];
    if (q != 0) qf = z8;

    // bpermute source byte-addresses (fixed per lane):
    //  dest (q, jj<4)  pulls lane l15 + 16*((2q)&3)
    //  dest (q, jj>=4) pulls lane l15 + 16*((2q+1)&3)
    const int srcA = (l15 + 16 * ((2 * q) & 3)) * 4;
    const int srcB = (l15 + 16 * ((2 * q + 1) & 3)) * 4;
    const bool qhi = (q >= 2);        // dest jt parity = q>>1

    f32x4 acc[4] = {zf, zf, zf, zf};
    float lsum = 0.f;                 // per-lane: all P values share i = l15

    const unsigned short* kbase = kws + (size_t)(b * NN + js * 512) * 8;
    const unsigned short* vbase = vfrag + (size_t)(b * 64 + js * 8) * 4096;

    for (int t = 0; t < 8; ++t) {
        const unsigned short* kt = kbase + (size_t)t * 4096;
        const unsigned short* vt = vbase + (size_t)t * 4096;

        i32x4 af[2];
        #pragma unroll
        for (int h = 0; h < 2; ++h) {           // a-frag halves: j in [h*32, h*32+32)
            float pe[2][4];
            #pragma unroll
            for (int j2 = 0; j2 < 2; ++j2) {    // jt planes within half
                const int jt = h * 2 + j2;
                // E^T = K.Q^T: A=K row (jt*16+l15); lanes q>0 hold garbage at
                // k>=8 but multiply qf=0 there.
                const short8 kf = *(const short8*)&kt[(jt * 16 + l15) * 8];
                const f32x4 e = __builtin_amdgcn_mfma_f32_16x16x32_bf16(kf, qf, zf, 0, 0, 0);
                #pragma unroll
                for (int r = 0; r < 4; ++r) {   // j = jt*16 + q*4 + r, i = l15
                    const float p = __builtin_amdgcn_exp2f(e[r]);
                    lsum += p;
                    pe[j2][r] = p;
                }
            }
            // pack both jt-planes (r pairs), bpermute, select by dest jt
            const int d00 = packbf(pe[0][0], pe[0][1]);
            const int d01 = packbf(pe[0][2], pe[0][3]);
            const int d10 = packbf(pe[1][0], pe[1][1]);
            const int d11 = packbf(pe[1][2], pe[1][3]);
            i32x4 a;
            {
                const int lo = __builtin_amdgcn_ds_bpermute(srcA, d00);
                const int hi = __builtin_amdgcn_ds_bpermute(srcA, d10);
                a[0] = qhi ? hi : lo;           // jj=0,1
            }
            {
                const int lo = __builtin_amdgcn_ds_bpermute(srcA, d01);
                const int hi = __builtin_amdgcn_ds_bpermute(srcA, d11);
                a[1] = qhi ? hi : lo;           // jj=2,3
            }
            {
                const int lo = __builtin_amdgcn_ds_bpermute(srcB, d00);
                const int hi = __builtin_amdgcn_ds_bpermute(srcB, d10);
                a[2] = qhi ? hi : lo;           // jj=4,5
            }
            {
                const int lo = __builtin_amdgcn_ds_bpermute(srcB, d01);
                const int hi = __builtin_amdgcn_ds_bpermute(srcB, d11);
                a[3] = qhi ? hi : lo;           // jj=6,7
            }
            af[h] = a;
        }
        const short8 a0 = __builtin_bit_cast(short8, af[0]);
        const short8 a1 = __builtin_bit_cast(short8, af[1]);

        // ---- PV: inline V fragment loads (L2-hot), 8 MFMA ----
        #pragma unroll
        for (int ct = 0; ct < 4; ++ct) {
            const short8 v0 = *(const short8*)&vt[((ct * 2 + 0) * 64 + lane) * 8];
            const short8 v1 = *(const short8*)&vt[((ct * 2 + 1) * 64 + lane) * 8];
            acc[ct] = __builtin_amdgcn_mfma_f32_16x16x32_bf16(a0, v0, acc[ct], 0, 0, 0);
            acc[ct] = __builtin_amdgcn_mfma_f32_16x16x32_bf16(a1, v1, acc[ct], 0, 0, 0);
        }
    }

    // ---- epilogue (wave-private) ----
    const int sb = js * BB + b;
    {
        float vv = lsum;                         // partial over this js's 512 j
        vv += __shfl_xor(vv, 16);
        vv += __shfl_xor(vv, 32);
        if (lane < 16)
            pl[(size_t)sb * NN + i0 + w * 16 + lane] = vv;
    }
    #pragma unroll
    for (int ct = 0; ct < 4; ++ct)
        #pragma unroll
        for (int r = 0; r < 4; ++r)
            olds[w][ct * 16 + l15][q * 4 + r] = acc[ct][r];

    // lane = output channel c; 16 i-values -> bf16, two dwordx4 stores
    const float* orow = &olds[w][lane][0];
    unsigned short* pb = pout + ((size_t)sb * 64 + lane) * NN + i0 + w * 16;
    uint4 pk[2];
    #pragma unroll
    for (int h = 0; h < 2; ++h) {
        unsigned pv[4];
        #pragma unroll
        for (int u = 0; u < 4; ++u) {
            unsigned lo = __float_as_uint(orow[h * 8 + u * 2 + 0]) >> 16;
            unsigned hi = __float_as_uint(orow[h * 8 + u * 2 + 1]) & 0xFFFF0000u;
            pv[u] = lo | hi;
        }
        pk[h] = make_uint4(pv[0], pv[1], pv[2], pv[3]);
    }
    *(uint4*)&pb[0] = pk[0];
    *(uint4*)&pb[8] = pk[1];
}

// ---------------------------------------------------------------------------
// Kernel 3: reduce 8 j-splits (bf16 partials), normalize, gamma*out + x1
// ---------------------------------------------------------------------------
__global__ __launch_bounds__(256) void final_kernel(
    const unsigned short* __restrict__ pout, const float* __restrict__ pl,
    const float* __restrict__ gamma,
    float* __restrict__ out)
{
    const int gid = blockIdx.x * 256 + threadIdx.x;   // 0..262143 (4-elt groups)
    const int b  = gid >> 16;
    const int c  = (gid >> 10) & 63;
    const int g4 = (gid & 1023) * 4;
    const float g = gamma[0];

    f32x4 s = {0.f, 0.f, 0.f, 0.f};
    f32x4 l = {0.f, 0.f, 0.f, 0.f};
    #pragma unroll
    for (int ss = 0; ss < JSPLIT; ++ss) {
        const ushort4 u = *(const ushort4*)&pout[(((size_t)(ss * BB + b)) * 64 + c) * NN + g4];
        s[0] += __uint_as_float((unsigned)u.x << 16);
        s[1] += __uint_as_float((unsigned)u.y << 16);
        s[2] += __uint_as_float((unsigned)u.z << 16);
        s[3] += __uint_as_float((unsigned)u.w << 16);
        l += *(const f32x4*)&pl[(size_t)(ss * BB + b) * NN + g4];
    }
    const size_t o0 = (size_t)gid * 4;
    f32x4 r = *(const f32x4*)&out[o0];
    #pragma unroll
    for (int u = 0; u < 4; ++u) r[u] += g * (s[u] / l[u]);
    *(f32x4*)&out[o0] = r;
}

// ---------------------------------------------------------------------------
extern "C" void kernel_launch(void* const* d_in, const int* in_sizes, int n_in,
                              void* d_out, int out_size, void* d_ws, size_t ws_size,
                              hipStream_t stream) {
    (void)in_sizes; (void)n_in; (void)out_size; (void)ws_size;
    const float* x  = (const float*)d_in[0];
    const float* Wq = (const float*)d_in[1];
    const float* bq = (const float*)d_in[2];
    const float* Wk = (const float*)d_in[3];
    const float* bk = (const float*)d_in[4];
    const float* Wv = (const float*)d_in[5];
    const float* bv = (const float*)d_in[6];
    const float* W1 = (const float*)d_in[7];
    const float* b1 = (const float*)d_in[8];
    const float* gm = (const float*)d_in[9];
    float* out = (float*)d_out;

    float* ws = (float*)d_ws;
    unsigned short* qb     = (unsigned short*)(ws);             // bf16
    unsigned short* kb     = (unsigned short*)(ws + 65536);     // bf16
    unsigned short* vb     = (unsigned short*)(ws + 131072);    // bf16 B-frags
    unsigned short* wfragg = (unsigned short*)(ws + 1179648);   // bf16 A-frags
    float*          bias   = ws + 1184256;
    unsigned short* pout16 = (unsigned short*)(ws + 1184400);   // bf16 partials
    float*          pl     = ws + 5378704;

    wsetup_kernel<<<36, 256, 0, stream>>>(Wq, bq, Wk, bk, Wv, bv, W1, b1,
                                          wfragg, bias);
    proj_kernel<<<1024, 256, 0, stream>>>(x, wfragg, bias, qb, kb, vb, out);
    attn_kernel<<<2048, 256, 0, stream>>>(qb, kb, vb, pout16, pl);
    final_kernel<<<1024, 256, 0, stream>>>(pout16, pl, gm, out);
}